// Round 2
// baseline (100.638 us; speedup 1.0000x reference)
//
#include <hip/hip_runtime.h>
#include <math.h>

#define HW_SZ 32768
#define C_SZ  256
#define L_SZ  5
#define CHW   (C_SZ * HW_SZ)     // 8,388,608 elements (int-safe)

typedef float vfloat4 __attribute__((ext_vector_type(4)));

// ---------------------------------------------------------------------------
// Single-pass fused kernel (v0 structure). Block = 512 threads (8 waves),
// owns 32 consecutive spatial locations n. All 5*256*32 floats live in
// registers (80 VGPR/thread):
//   lane = 8*ci + ni4 ; thread's n-range = blk*32 + 4*ni4 .. +3 (one float4)
//   thread's channels: c = 32*wave + 8*j + ci, j = 0..3
// Phases: load+dot -> shfl_xor butterfly over ci -> LDS cross-wave reduce ->
// softmax/gate (32 threads) -> broadcast mask -> scale regs -> stores.
//
// R2 change vs v0: stores are PLAIN (not nontemporal). Evidence: v0's nt
// store burst wrote 212 MB to HBM for 168 MB logical (+26%) — eager nt
// eviction pushed lone 128-B lines into 256-B HBM atoms (the adjacent line
// belongs to block+-1, far away in time) -> RMW amplification. Plain stores
// let dirty lines merge in TCC/L3 and let L3 act as a write buffer that
// drains during the next block generation's read phase (R/W mixing at HBM).
// ---------------------------------------------------------------------------
__global__ __launch_bounds__(512, 4) void is_fused_kernel(
    const float* __restrict__ x,      // (L, C, HW)
    const float* __restrict__ mlp_w,  // (1, C)
    const float* __restrict__ mlp_b,  // (1,)
    float* __restrict__ out)          // (L, C, HW)
{
    __shared__ float w_sh[C_SZ];
    __shared__ float part[8][8][8][5];   // [wave][ni4][val k][n-comp], pad 4->5
    __shared__ float m_sh[32];

    const int tid  = threadIdx.x;
    const int wv   = tid >> 6;
    const int lane = tid & 63;
    const int ci   = lane >> 3;
    const int ni4  = lane & 7;
    const int n0   = blockIdx.x * 32 + ni4 * 4;

    if (tid < C_SZ) w_sh[tid] = mlp_w[tid];
    __syncthreads();

    const int cbase = 32 * wv + ci;          // + 8*j
    const float* bp = x + cbase * HW_SZ + n0;

    // ---- phase 1: load everything (20 independent float4 loads) ----
    vfloat4 v[5][4];
    #pragma unroll
    for (int l = 0; l < 5; ++l)
        #pragma unroll
        for (int j = 0; j < 4; ++j)
            v[l][j] = *(const vfloat4*)(bp + l * CHW + j * 8 * HW_SZ);

    // ---- phase 2: per-thread partial dots (4 channels, 4 n each) ----
    vfloat4 s[4] = {{0,0,0,0},{0,0,0,0},{0,0,0,0},{0,0,0,0}};
    vfloat4 t[4] = {{0,0,0,0},{0,0,0,0},{0,0,0,0},{0,0,0,0}};
    #pragma unroll
    for (int j = 0; j < 4; ++j) {
        const float wc = w_sh[cbase + 8 * j];
        #pragma unroll
        for (int k = 0; k < 4; ++k) {
            s[k] += v[0][j] * v[k + 1][j];
            t[k] += wc      * v[k + 1][j];
        }
    }

    // ---- phase 3: butterfly reduce over ci (lane xor 8,16,32) ----
    #pragma unroll
    for (int m = 8; m <= 32; m <<= 1) {
        #pragma unroll
        for (int k = 0; k < 4; ++k) {
            #pragma unroll
            for (int c = 0; c < 4; ++c) {
                s[k][c] += __shfl_xor(s[k][c], m, 64);
                t[k][c] += __shfl_xor(t[k][c], m, 64);
            }
        }
    }
    if (ci == 0) {
        #pragma unroll
        for (int k = 0; k < 4; ++k)
            #pragma unroll
            for (int c = 0; c < 4; ++c) {
                part[wv][ni4][k][c]     = s[k][c];
                part[wv][ni4][k + 4][c] = t[k][c];
            }
    }
    __syncthreads();

    // ---- phase 4: cross-wave reduce + softmax + gate (32 threads, 1/n) ----
    if (tid < 32) {
        const int g = tid >> 2, cc = tid & 3;
        float ss[4] = {0, 0, 0, 0}, tt[4] = {0, 0, 0, 0};
        #pragma unroll
        for (int w8 = 0; w8 < 8; ++w8) {
            #pragma unroll
            for (int k = 0; k < 4; ++k) {
                ss[k] += part[w8][g][k][cc];
                tt[k] += part[w8][g][k + 4][cc];
            }
        }
        const float scale = 0.0625f;   // 1/sqrt(256)
        #pragma unroll
        for (int k = 0; k < 4; ++k) ss[k] *= scale;

        const float smax = fmaxf(fmaxf(ss[0], ss[1]), fmaxf(ss[2], ss[3]));
        const float p0 = expf(ss[0] - smax);
        const float p1 = expf(ss[1] - smax);
        const float p2 = expf(ss[2] - smax);
        const float p3 = expf(ss[3] - smax);
        const float z  = (p0 * tt[0] + p1 * tt[1] + p2 * tt[2] + p3 * tt[3])
                         / ((p0 + p1) + (p2 + p3)) + mlp_b[0];
        // sigmoid(relu(z)) > 0.5  <=>  z > 0  (exact)
        m_sh[tid] = (z > 0.f) ? 1.f : 0.f;
    }
    __syncthreads();

    // ---- phase 5: scale + store (20 float4 PLAIN stores) ----
    const int nl = ni4 * 4;
    vfloat4 m4;
    m4.x = m_sh[nl];     m4.y = m_sh[nl + 1];
    m4.z = m_sh[nl + 2]; m4.w = m_sh[nl + 3];

    float* op = out + cbase * HW_SZ + n0;
    #pragma unroll
    for (int j = 0; j < 4; ++j)
        *(vfloat4*)(op + j * 8 * HW_SZ) = v[0][j];
    #pragma unroll
    for (int l = 1; l < 5; ++l)
        #pragma unroll
        for (int j = 0; j < 4; ++j)
            *(vfloat4*)(op + l * CHW + j * 8 * HW_SZ) = v[l][j] * m4;
}

extern "C" void kernel_launch(void* const* d_in, const int* in_sizes, int n_in,
                              void* d_out, int out_size, void* d_ws, size_t ws_size,
                              hipStream_t stream) {
    const float* x = (const float*)d_in[0];   // node_feature (5,256,128,256)
    const float* w = (const float*)d_in[1];   // mlp_w (1,256)
    const float* b = (const float*)d_in[2];   // mlp_b (1,)
    float* out = (float*)d_out;

    hipLaunchKernelGGL(is_fused_kernel, dim3(HW_SZ / 32), dim3(512), 0, stream,
                       x, w, b, out);
}

// Round 3
// 65.436 us; speedup vs baseline: 1.5380x; 1.5380x over previous
//
#include <hip/hip_runtime.h>
#include <math.h>

#define HW_SZ 32768
#define C_SZ  256
#define L_SZ  5
#define CHW   (C_SZ * HW_SZ)     // 8,388,608 elements (int-safe)

typedef float vfloat4 __attribute__((ext_vector_type(4)));

// ---------------------------------------------------------------------------
// R3: atom-complete stores. Block = 1024 threads (16 waves), owns 64
// consecutive spatial n. Per-thread payload identical to v0 (80 floats:
// 4 channels x 5 planes x 4 n), only the lane geometry changes:
//   lane = 16*ci4 + ni16 ; thread's n-range = blk*64 + 4*ni16 .. +3
//   thread's channels: c = 16*wv + 4*j + ci4, j = 0..3
// Now each wave store covers 4 rows x 256 B *aligned, complete* segments ->
// every touched 256-B HBM atom is fully written by ONE instruction. This
// kills v0's +26% nt write amplification (212 MB for 168 MB logical), which
// R1 proved was a partial-atom timing artifact (spread stores wrote 168).
// R2 proved stores must stay nontemporal (L2 path = 100 us disaster).
// Ego plane (maskless) is stored right after the dot pass -> ~34 MB of
// writes overlap the reduce/softmax phase.
// Phases: load+dot -> ego store -> 2-stage shfl butterfly over ci4 ->
// LDS cross-wave reduce -> softmax/gate (64 threads) -> masked nt stores.
// ---------------------------------------------------------------------------
__global__ __launch_bounds__(1024, 1) void is_fused_kernel(
    const float* __restrict__ x,      // (L, C, HW)
    const float* __restrict__ mlp_w,  // (1, C)
    const float* __restrict__ mlp_b,  // (1,)
    float* __restrict__ out)          // (L, C, HW)
{
    __shared__ float w_sh[C_SZ];
    __shared__ float part[16][16][8][5];  // [wave][ni16][val k][n-comp], pad 4->5
    __shared__ float m_sh[64];

    const int tid  = threadIdx.x;
    const int wv   = tid >> 6;          // 0..15
    const int lane = tid & 63;
    const int ci4  = lane >> 4;         // 0..3  (channel slice within wave)
    const int ni16 = lane & 15;         // 0..15 (n-position, 4 floats each)
    const int n0   = blockIdx.x * 64 + ni16 * 4;

    if (tid < C_SZ) w_sh[tid] = mlp_w[tid];
    __syncthreads();

    const int cb = 16 * wv + ci4;       // + 4*j
    const float* bp = x   + cb * HW_SZ + n0;
    float*       op = out + cb * HW_SZ + n0;

    // ---- phase 1: load everything (20 independent float4 loads) ----
    vfloat4 v[5][4];
    #pragma unroll
    for (int l = 0; l < 5; ++l)
        #pragma unroll
        for (int j = 0; j < 4; ++j)
            v[l][j] = *(const vfloat4*)(bp + l * CHW + j * 4 * HW_SZ);

    // ---- phase 2: per-thread partial dots (4 channels, 4 n each) ----
    vfloat4 s[4] = {{0,0,0,0},{0,0,0,0},{0,0,0,0},{0,0,0,0}};
    vfloat4 t[4] = {{0,0,0,0},{0,0,0,0},{0,0,0,0},{0,0,0,0}};
    #pragma unroll
    for (int j = 0; j < 4; ++j) {
        const float wc = w_sh[cb + 4 * j];
        #pragma unroll
        for (int k = 0; k < 4; ++k) {
            s[k] += v[0][j] * v[k + 1][j];
            t[k] += wc      * v[k + 1][j];
        }
    }

    // ---- ego store early (maskless) — overlaps the reduce phase ----
    #pragma unroll
    for (int j = 0; j < 4; ++j)
        __builtin_nontemporal_store(v[0][j], (vfloat4*)(op + j * 4 * HW_SZ));

    // ---- phase 3: butterfly reduce over ci4 (lane xor 16, 32) ----
    #pragma unroll
    for (int m = 16; m <= 32; m <<= 1) {
        #pragma unroll
        for (int k = 0; k < 4; ++k) {
            #pragma unroll
            for (int c = 0; c < 4; ++c) {
                s[k][c] += __shfl_xor(s[k][c], m, 64);
                t[k][c] += __shfl_xor(t[k][c], m, 64);
            }
        }
    }
    if (ci4 == 0) {
        #pragma unroll
        for (int k = 0; k < 4; ++k)
            #pragma unroll
            for (int c = 0; c < 4; ++c) {
                part[wv][ni16][k][c]     = s[k][c];
                part[wv][ni16][k + 4][c] = t[k][c];
            }
    }
    __syncthreads();

    // ---- phase 4: cross-wave reduce + softmax + gate (64 threads, 1/n) ----
    if (tid < 64) {
        const int g = tid >> 2, cc = tid & 3;
        float ss[4] = {0, 0, 0, 0}, tt[4] = {0, 0, 0, 0};
        #pragma unroll
        for (int w8 = 0; w8 < 16; ++w8) {
            #pragma unroll
            for (int k = 0; k < 4; ++k) {
                ss[k] += part[w8][g][k][cc];
                tt[k] += part[w8][g][k + 4][cc];
            }
        }
        const float scale = 0.0625f;   // 1/sqrt(256)
        #pragma unroll
        for (int k = 0; k < 4; ++k) ss[k] *= scale;

        const float smax = fmaxf(fmaxf(ss[0], ss[1]), fmaxf(ss[2], ss[3]));
        const float p0 = expf(ss[0] - smax);
        const float p1 = expf(ss[1] - smax);
        const float p2 = expf(ss[2] - smax);
        const float p3 = expf(ss[3] - smax);
        const float z  = (p0 * tt[0] + p1 * tt[1] + p2 * tt[2] + p3 * tt[3])
                         / ((p0 + p1) + (p2 + p3)) + mlp_b[0];
        // sigmoid(relu(z)) > 0.5  <=>  z > 0  (exact)
        m_sh[tid] = (z > 0.f) ? 1.f : 0.f;
    }
    __syncthreads();

    // ---- phase 5: scale + store (16 float4 NT stores, atom-complete) ----
    const int nl = ni16 * 4;
    vfloat4 m4;
    m4.x = m_sh[nl];     m4.y = m_sh[nl + 1];
    m4.z = m_sh[nl + 2]; m4.w = m_sh[nl + 3];

    #pragma unroll
    for (int l = 1; l < 5; ++l)
        #pragma unroll
        for (int j = 0; j < 4; ++j)
            __builtin_nontemporal_store(v[l][j] * m4,
                                        (vfloat4*)(op + l * CHW + j * 4 * HW_SZ));
}

extern "C" void kernel_launch(void* const* d_in, const int* in_sizes, int n_in,
                              void* d_out, int out_size, void* d_ws, size_t ws_size,
                              hipStream_t stream) {
    const float* x = (const float*)d_in[0];   // node_feature (5,256,128,256)
    const float* w = (const float*)d_in[1];   // mlp_w (1,256)
    const float* b = (const float*)d_in[2];   // mlp_b (1,)
    float* out = (float*)d_out;

    hipLaunchKernelGGL(is_fused_kernel, dim3(HW_SZ / 64), dim3(1024), 0, stream,
                       x, w, b, out);
}